// Round 3
// baseline (581.095 us; speedup 1.0000x reference)
//
#include <hip/hip_runtime.h>
#include <stdint.h>

// Problem constants (from reference)
#define B_  32
#define T_  1024
#define C_  512
#define H_  1024
#define SCALE_ 32.0f   // sqrt(1024)

// Tiling
#define BM 128
#define BN 128
#define BK 32
#define ROWE 32              // elems per LDS row, no pad; XOR swizzle for banks
#define NSTEP (C_ / BK)      // 16
#define NTHR 512             // 8 waves

typedef __attribute__((ext_vector_type(8))) short frag_ab;   // 8 bf16 (4 VGPRs)
typedef __attribute__((ext_vector_type(4))) float frag_cd;   // 4 fp32

// Packed f32x2 -> bf16x2 (RNE), single instruction, schedulable (non-volatile).
__device__ __forceinline__ uint32_t cvtpk_bf16(float lo, float hi) {
    uint32_t r;
    asm("v_cvt_pk_bf16_f32 %0, %1, %2" : "=v"(r) : "v"(lo), "v"(hi));
    return r;
}

__device__ __forceinline__ void cvt4_store(unsigned short* dst, float4 v) {
    uint2 p;
    p.x = cvtpk_bf16(v.x, v.y);
    p.y = cvtpk_bf16(v.z, v.w);
    *(uint2*)dst = p;   // 8 B aligned
}

// Raw barrier: per-wave LDS drain + s_barrier, NO vmcnt(0) drain. Global
// prefetch loads (register-destined) legitimately stay in flight across it.
#define BARRIER() do { \
    asm volatile("s_waitcnt lgkmcnt(0)" ::: "memory"); \
    __builtin_amdgcn_s_barrier(); \
    asm volatile("" ::: "memory"); \
} while (0)

// (512, 8): force combined VGPR+AGPR <= 64 -> 8 waves/SIMD -> 4 blocks/CU
// (the occupancy granule: 65..128 regs costs a halving to 4 waves/SIMD,
// which is what capped rounds 0-2 at 2 resident blocks / ~42%).
__global__ __launch_bounds__(NTHR, 8)
void NeuralEmbeddingLayer_kernel(
    const float* __restrict__ features,     // [B,T,C]
    const int*   __restrict__ ts,           // [B,T]
    const int*   __restrict__ date_idx,     // [B]
    const float* __restrict__ spikes,       // [N_DATES,H,C]
    const float* __restrict__ spikes_bias,  // [N_DATES]
    const float* __restrict__ pos,          // [MAX_F,H]
    float*       __restrict__ out)          // [B,T,H]
{
    const int tid = threadIdx.x;
    const int bid = blockIdx.x;

    // XCD-clustered mapping: one XCD gets whole samples.
    const int xcd   = bid & 7;
    const int local = bid >> 3;               // 0..255 within this XCD
    const int b     = ((local >> 6) << 3) + xcd;  // 4 samples per XCD
    const int tile  = local & 63;
    const int t0 = (tile >> 3) * BM;
    const int h0 = (tile & 7) * BN;

    const int   date = date_idx[b];
    const float bias = spikes_bias[date];
    // Uniform (SGPR) base pointers; per-lane part lives in 2 shared voffsets.
    const char* Abase = (const char*)features + ((size_t)b * T_ + t0) * C_ * 4;
    const char* Wbase = (const char*)spikes   + ((size_t)date * H_ + h0) * C_ * 4;

    __shared__ __align__(16) unsigned short ldsA[2][BM * ROWE]; // 8 KB each
    __shared__ __align__(16) unsigned short ldsB[2][BM * ROWE];
    __shared__ int lds_ts[BM];

    // ---- static per-thread staging coordinates ----
    // tile: 128 rows x 8 float4-groups = 1024 groups; 512 threads -> 2 each,
    // rows r0 and r0+64. Swizzle term invariant in i (64 ≡ 0 mod 4 on (row>>1)&3).
    const int r0  = tid >> 3;            // 0..63
    const int jj  = tid & 7;
    const int sw0 = (jj >> 1) ^ ((r0 >> 1) & 3);
    const int offBase = r0 * ROWE + sw0 * 8 + (jj & 1) * 4;
    // byte voffsets shared by A and W; K-step offset is a compile-time imm
    const int voffLo = r0 * (C_ * 4) + jj * 16;
    const int voffHi = voffLo + 64 * (C_ * 4);

    // ONE prefetch set (16 VGPRs), distance-1: loads for step ks+1 issue at
    // the top of iter ks, staged at the bottom. TLP (8 waves/SIMD) hides the
    // residual latency — round 1/2 proved deeper SW pipelining is null here.
    float4 pA[2], pB[2];

    auto loadset = [&](int kbyte) {
        pA[0] = *(const float4*)(Abase + voffLo + kbyte);
        pA[1] = *(const float4*)(Abase + voffHi + kbyte);
        pB[0] = *(const float4*)(Wbase + voffLo + kbyte);
        pB[1] = *(const float4*)(Wbase + voffHi + kbyte);
    };
    auto stageset = [&](int buf) {
        cvt4_store(&ldsA[buf][offBase], pA[0]);
        cvt4_store(&ldsA[buf][offBase + 64 * ROWE], pA[1]);
        cvt4_store(&ldsB[buf][offBase], pB[0]);
        cvt4_store(&ldsB[buf][offBase + 64 * ROWE], pB[1]);
    };

    // ---- prologue: stage step 0 ----
    int tsval = 0;
    if (tid < BM) tsval = ts[b * T_ + t0 + tid];
    loadset(0);
    if (tid < BM) lds_ts[tid] = tsval;
    stageset(0);
    BARRIER();

    // ---- wave/lane decode: 8 waves in 2(M) x 4(N), per-wave 64x32 tile ----
    const int wave = tid >> 6;        // 0..7
    const int lane = tid & 63;
    const int quad = lane >> 4;       // k-halfgroup for A/B frags; row-quad for C/D
    const int m_   = lane & 15;
    const int wm = (wave >> 2) * 64;  // 0 or 64  (M / t)
    const int wn = (wave & 3) * 32;   // 0,32,64,96  (N / h)

    frag_cd acc[4][2] = {};           // 32 AGPRs

    // ---- K loop: dbuf LDS, distance-1 register prefetch, raw barriers ----
#pragma unroll
    for (int ks = 0; ks < NSTEP; ++ks) {
        const int buf = ks & 1;

        if (ks + 1 < NSTEP) loadset((ks + 1) * (BK * 4));

        frag_ab bfrag[2];
#pragma unroll
        for (int ni = 0; ni < 2; ++ni) {
            int row = wn + ni * 16 + m_;
            int sw  = (row >> 1) & 3;
            bfrag[ni] = *(const frag_ab*)&ldsB[buf][row * ROWE + ((quad ^ sw) * 8)];
        }
#pragma unroll
        for (int mi = 0; mi < 4; ++mi) {
            int row = wm + mi * 16 + m_;
            int sw  = (row >> 1) & 3;
            frag_ab af = *(const frag_ab*)&ldsA[buf][row * ROWE + ((quad ^ sw) * 8)];
#pragma unroll
            for (int ni = 0; ni < 2; ++ni)
                acc[mi][ni] = __builtin_amdgcn_mfma_f32_16x16x32_bf16(
                    af, bfrag[ni], acc[mi][ni], 0, 0, 0);
        }

        if (ks + 1 < NSTEP) {
            stageset(buf ^ 1);       // vmcnt wait lands here, after the MFMAs
            BARRIER();
        }
    }

    // ---- epilogue: acc*SCALE + bias + pos[ts[t]][h] ----
    // C/D layout (m89-verified): col = lane&15 (n/h), row = quad*4 + reg (m/t)
#pragma unroll
    for (int mi = 0; mi < 4; ++mi) {
#pragma unroll
        for (int r = 0; r < 4; ++r) {
            int trow = wm + mi * 16 + quad * 4 + r;
            int tsv  = lds_ts[trow];
            const float* prow = pos + (size_t)tsv * H_ + h0;
            size_t orow = ((size_t)b * T_ + (t0 + trow)) * (size_t)H_ + h0;
#pragma unroll
            for (int ni = 0; ni < 2; ++ni) {
                int col = wn + ni * 16 + m_;
                out[orow + col] = acc[mi][ni][r] * SCALE_ + bias + prow[col];
            }
        }
    }
}

extern "C" void kernel_launch(void* const* d_in, const int* in_sizes, int n_in,
                              void* d_out, int out_size, void* d_ws, size_t ws_size,
                              hipStream_t stream) {
    const float* features  = (const float*)d_in[0];
    const int*   ts        = (const int*)d_in[1];
    const int*   date_idx  = (const int*)d_in[2];
    const float* spikes    = (const float*)d_in[3];
    const float* sbias     = (const float*)d_in[4];
    const float* pos       = (const float*)d_in[5];
    float*       out       = (float*)d_out;

    dim3 grid(B_ * (T_ / BM) * (H_ / BN));   // 32 * 8 * 8 = 2048
    NeuralEmbeddingLayer_kernel<<<grid, NTHR, 0, stream>>>(
        features, ts, date_idx, spikes, sbias, pos, out);
}